// Round 14
// baseline (177.593 us; speedup 1.0000x reference)
//
#include <hip/hip_runtime.h>

#define NN 4096
#define FF 512
#define DD 64
#define HH 8
#define CC 40
#define HD (HH * DD)   // 512
#define CP 64          // padded class dim
#define MAXDEG 128
#define ALPHA 0.2f

// f32 GEMM tiling (l2)
#define BM 64
#define BN 64
#define BK 16
#define SK2 8
#define KH2 (FF / SK2) // 64 per split

typedef __attribute__((ext_vector_type(8))) short bf16x8;
typedef __attribute__((ext_vector_type(4))) float f32x4;

__device__ __forceinline__ float bf2f(unsigned short u) {
    union { unsigned int i; float f; } v;
    v.i = ((unsigned int)u) << 16;
    return v.f;
}

__device__ __forceinline__ unsigned short f2bf(float f) {
    union { float f; unsigned int u; } v;
    v.f = f;
    unsigned int r = v.u + 0x7fffu + ((v.u >> 16) & 1u);  // RNE
    return (unsigned short)(r >> 16);
}

__device__ __forceinline__ float wave_sum(float v) {
    #pragma unroll
    for (int off = 32; off; off >>= 1) v += __shfl_xor(v, off, 64);
    return v;
}

__device__ __forceinline__ float wave_max(float v) {
    #pragma unroll
    for (int off = 32; off; off >>= 1) v = fmaxf(v, __shfl_xor(v, off, 64));
    return v;
}

__device__ __forceinline__ float read_f(const void* src, int i, int isBf16) {
    if (isBf16) return bf2f(((const unsigned short*)src)[i]);
    return ((const float*)src)[i];
}

// Inline x-dtype sniff: every block reads the SAME x[0:1024] words (4KB,
// L2-hit) -> all blocks reach the same verdict deterministically.
__device__ __forceinline__ int sniff_x(const void* xraw, int tid, int* fS) {
    if (tid == 0) *fS = 1;
    __syncthreads();
    int bad = 0;
    const unsigned int* xw = (const unsigned int*)xraw;
    #pragma unroll
    for (int q = 0; q < 4; q++) {
        unsigned int w = xw[(tid & 255) * 4 + q];
        unsigned int e0 = (w >> 7) & 0xffu;
        unsigned int e1 = (w >> 23) & 0xffu;
        if (e0 >= 0x90u || e1 >= 0x90u) bad = 1;
    }
    if (bad) *fS = 0;
    __syncthreads();
    return *fS;
}

// ---------------- prep: build_nbr + conversions + zeroing in ONE launch -----
// blocks [0, NN):      neighbor list for row blockIdx.x (inline adj sniff)
// blocks [NN, NN+64):  W1 -> W1bt{h,l} [H*D][F] bf16 split (coalesced output)
// blocks [NN+64, ...): W2p zero-pad + a-vectors + zero h2/d1/d2 (l2 atomics)
__global__ __launch_bounds__(256) void prep(const unsigned char* __restrict__ adj,
                                            const void* __restrict__ x,
                                            const void* __restrict__ W1,
                                            const void* __restrict__ W2,
                                            const void* __restrict__ a1s,
                                            const void* __restrict__ a1d,
                                            const void* __restrict__ a2s,
                                            const void* __restrict__ a2d,
                                            int* __restrict__ nbr,
                                            int* __restrict__ deg,
                                            unsigned short* __restrict__ W1bth,
                                            unsigned short* __restrict__ W1btl,
                                            float* __restrict__ W2p,
                                            float* __restrict__ a1sf,
                                            float* __restrict__ a1df,
                                            float* __restrict__ a2sf,
                                            float* __restrict__ a2df,
                                            float* __restrict__ h2,
                                            float* __restrict__ d1,
                                            float* __restrict__ d2) {
    __shared__ int cnt;
    __shared__ int fS;
    int t = threadIdx.x;
    int blk = blockIdx.x;

    if (blk < NN) {
        // ---- build_nbr; adj elem-size sniff: byte t*(NN+1) valid both ways.
        // Byte-bool: diagonal -> all 1. Int32: t%4!=0 hits a zero byte-lane.
        if (t == 0) { cnt = 0; fS = 1; }
        __syncthreads();
        if (adj[(size_t)t * (NN + 1)] == 0) fS = 0;  // benign race
        __syncthreads();
        int isByte = fS;
        int i = blk;
        if (isByte) {
            uint4 v = ((const uint4*)(adj + (size_t)i * NN))[t];
            unsigned int u[4] = { v.x, v.y, v.z, v.w };
            int base = t * 16;
            #pragma unroll
            for (int q = 0; q < 4; q++) {
                #pragma unroll
                for (int b = 0; b < 4; b++) {
                    if ((u[q] >> (8 * b)) & 0xffu) {
                        int p = atomicAdd(&cnt, 1);
                        if (p < MAXDEG) nbr[(size_t)i * MAXDEG + p] = base + q * 4 + b;
                    }
                }
            }
        } else {
            const int4* row = (const int4*)((const int*)adj + (size_t)i * NN);
            #pragma unroll
            for (int q = 0; q < 4; q++) {
                int idx4 = q * 256 + t;
                int4 v = row[idx4];
                int base = idx4 * 4;
                if (v.x) { int p = atomicAdd(&cnt, 1); if (p < MAXDEG) nbr[(size_t)i * MAXDEG + p] = base; }
                if (v.y) { int p = atomicAdd(&cnt, 1); if (p < MAXDEG) nbr[(size_t)i * MAXDEG + p] = base + 1; }
                if (v.z) { int p = atomicAdd(&cnt, 1); if (p < MAXDEG) nbr[(size_t)i * MAXDEG + p] = base + 2; }
                if (v.w) { int p = atomicAdd(&cnt, 1); if (p < MAXDEG) nbr[(size_t)i * MAXDEG + p] = base + 3; }
            }
        }
        __syncthreads();
        if (t == 0) deg[i] = min(cnt, MAXDEG);
        return;
    }

    int bf = sniff_x(x, t, &fS);

    if (blk < NN + 64) {
        // ---- W1 transpose: thread owns 16 consecutive OUTPUT elems
        // (32B coalesced store per array); reads stride-DD, L2-resident.
        int b = blk - NN;                       // 0..63
        int ob = b * 4096 + t * 16;
        int row = ob >> 9;                      // hd*64 + d
        int f0 = ob & 511;
        int hd = row >> 6, d = row & 63;
        unsigned short hi[16], lo[16];
        #pragma unroll
        for (int q = 0; q < 16; q++) {
            float v = read_f(W1, (hd * FF + f0 + q) * DD + d, bf);
            unsigned short h16 = f2bf(v);
            hi[q] = h16;
            lo[q] = f2bf(v - bf2f(h16));
        }
        #pragma unroll
        for (int q = 0; q < 16; q++) {
            W1bth[(size_t)row * FF + f0 + q] = hi[q];
            W1btl[(size_t)row * FF + f0 + q] = lo[q];
        }
        return;
    }

    // ---- small tensors + zeroing for l2 atomic accumulation
    int i = (blk - NN - 64) * 256 + t;
    const int nW2p = HD * CP;          // 32,768
    const int nA1 = HD;                // 512
    const int nH2 = NN * CC;           // 163,840
    if (i < nW2p) {
        int k = i / CP, c = i % CP;
        W2p[i] = (c < CC) ? read_f(W2, k * CC + c, bf) : 0.f;
        return;
    }
    i -= nW2p;
    if (i < nA1) { a1sf[i] = read_f(a1s, i, bf); return; }
    i -= nA1;
    if (i < nA1) { a1df[i] = read_f(a1d, i, bf); return; }
    i -= nA1;
    if (i < CC) { a2sf[i] = read_f(a2s, i, bf); return; }
    i -= CC;
    if (i < CC) { a2df[i] = read_f(a2d, i, bf); return; }
    i -= CC;
    if (i < nH2) { h2[i] = 0.f; return; }
    i -= nH2;
    if (i < NN) { d1[i] = 0.f; return; }
    i -= NN;
    if (i < NN) { d2[i] = 0.f; return; }
}

// ------ l1 GEMM via MFMA bf16x3, native x; si/sj via LDS (no atomics) -------
__global__ __launch_bounds__(256) void l1_gemm(const void* __restrict__ xraw,
                                               const unsigned short* __restrict__ W1bth,
                                               const unsigned short* __restrict__ W1btl,
                                               const float* __restrict__ a1sf,
                                               const float* __restrict__ a1df,
                                               unsigned short* __restrict__ hb,
                                               float* __restrict__ si,
                                               float* __restrict__ sj) {
    __shared__ __align__(16) unsigned short Ah[64][40];
    __shared__ __align__(16) unsigned short Al[64][40];
    __shared__ __align__(16) unsigned short Bh[64][40];
    __shared__ __align__(16) unsigned short Bl[64][40];
    __shared__ int fS;

    int bm = blockIdx.x, hd = blockIdx.y;
    int tid = threadIdx.x;
    int isBf16 = sniff_x(xraw, tid, &fS);

    int wave = tid >> 6, lane = tid & 63;
    int wm = wave >> 1, wn = wave & 1;
    int lr = lane & 15, lg = lane >> 4;
    int srow = tid >> 2;
    int sseg = (tid & 3) * 8;

    const unsigned short* wAp = W1bth + (size_t)(hd * 64 + srow) * FF + sseg;
    const unsigned short* wBp = W1btl + (size_t)(hd * 64 + srow) * FF + sseg;

    f32x4 acc[2][2];
    #pragma unroll
    for (int r = 0; r < 2; r++)
        #pragma unroll
        for (int c = 0; c < 2; c++) acc[r][c] = (f32x4){0.f, 0.f, 0.f, 0.f};

    if (isBf16) {
        const unsigned short* xp = (const unsigned short*)xraw
                                 + (size_t)(bm * 64 + srow) * FF + sseg;
        uint4 ra = *(const uint4*)xp;
        uint4 rb = *(const uint4*)wAp;
        for (int kk = 0; kk < FF; kk += 32) {
            __syncthreads();
            *(uint4*)&Ah[srow][sseg] = ra;
            *(uint4*)&Bh[srow][sseg] = rb;
            __syncthreads();
            int kn = (kk + 32 < FF) ? kk + 32 : kk;
            ra = *(const uint4*)(xp + kn);
            rb = *(const uint4*)(wAp + kn);
            bf16x8 a0 = *(const bf16x8*)&Ah[wm * 32 + lr][lg * 8];
            bf16x8 a1 = *(const bf16x8*)&Ah[wm * 32 + 16 + lr][lg * 8];
            bf16x8 b0 = *(const bf16x8*)&Bh[wn * 32 + lr][lg * 8];
            bf16x8 b1 = *(const bf16x8*)&Bh[wn * 32 + 16 + lr][lg * 8];
            acc[0][0] = __builtin_amdgcn_mfma_f32_16x16x32_bf16(a0, b0, acc[0][0], 0, 0, 0);
            acc[0][1] = __builtin_amdgcn_mfma_f32_16x16x32_bf16(a0, b1, acc[0][1], 0, 0, 0);
            acc[1][0] = __builtin_amdgcn_mfma_f32_16x16x32_bf16(a1, b0, acc[1][0], 0, 0, 0);
            acc[1][1] = __builtin_amdgcn_mfma_f32_16x16x32_bf16(a1, b1, acc[1][1], 0, 0, 0);
        }
    } else {
        const float* xp = (const float*)xraw + (size_t)(bm * 64 + srow) * FF + sseg;
        float4 ra0 = *(const float4*)xp;
        float4 ra1 = *(const float4*)(xp + 4);
        uint4 rbh = *(const uint4*)wAp;
        uint4 rbl = *(const uint4*)wBp;
        for (int kk = 0; kk < FF; kk += 32) {
            __syncthreads();
            union { unsigned short s[8]; uint4 v; } uh, ul;
            float fv[8] = { ra0.x, ra0.y, ra0.z, ra0.w, ra1.x, ra1.y, ra1.z, ra1.w };
            #pragma unroll
            for (int q = 0; q < 8; q++) {
                unsigned short h16 = f2bf(fv[q]);
                uh.s[q] = h16;
                ul.s[q] = f2bf(fv[q] - bf2f(h16));
            }
            *(uint4*)&Ah[srow][sseg] = uh.v;
            *(uint4*)&Al[srow][sseg] = ul.v;
            *(uint4*)&Bh[srow][sseg] = rbh;
            *(uint4*)&Bl[srow][sseg] = rbl;
            __syncthreads();
            int kn = (kk + 32 < FF) ? kk + 32 : kk;
            ra0 = *(const float4*)(xp + kn);
            ra1 = *(const float4*)(xp + kn + 4);
            rbh = *(const uint4*)(wAp + kn);
            rbl = *(const uint4*)(wBp + kn);

            bf16x8 a_h0 = *(const bf16x8*)&Ah[wm * 32 + lr][lg * 8];
            bf16x8 a_h1 = *(const bf16x8*)&Ah[wm * 32 + 16 + lr][lg * 8];
            bf16x8 a_l0 = *(const bf16x8*)&Al[wm * 32 + lr][lg * 8];
            bf16x8 a_l1 = *(const bf16x8*)&Al[wm * 32 + 16 + lr][lg * 8];
            bf16x8 b_h0 = *(const bf16x8*)&Bh[wn * 32 + lr][lg * 8];
            bf16x8 b_h1 = *(const bf16x8*)&Bh[wn * 32 + 16 + lr][lg * 8];
            bf16x8 b_l0 = *(const bf16x8*)&Bl[wn * 32 + lr][lg * 8];
            bf16x8 b_l1 = *(const bf16x8*)&Bl[wn * 32 + 16 + lr][lg * 8];

            acc[0][0] = __builtin_amdgcn_mfma_f32_16x16x32_bf16(a_h0, b_h0, acc[0][0], 0, 0, 0);
            acc[0][1] = __builtin_amdgcn_mfma_f32_16x16x32_bf16(a_h0, b_h1, acc[0][1], 0, 0, 0);
            acc[1][0] = __builtin_amdgcn_mfma_f32_16x16x32_bf16(a_h1, b_h0, acc[1][0], 0, 0, 0);
            acc[1][1] = __builtin_amdgcn_mfma_f32_16x16x32_bf16(a_h1, b_h1, acc[1][1], 0, 0, 0);
            acc[0][0] = __builtin_amdgcn_mfma_f32_16x16x32_bf16(a_h0, b_l0, acc[0][0], 0, 0, 0);
            acc[0][1] = __builtin_amdgcn_mfma_f32_16x16x32_bf16(a_h0, b_l1, acc[0][1], 0, 0, 0);
            acc[1][0] = __builtin_amdgcn_mfma_f32_16x16x32_bf16(a_h1, b_l0, acc[1][0], 0, 0, 0);
            acc[1][1] = __builtin_amdgcn_mfma_f32_16x16x32_bf16(a_h1, b_l1, acc[1][1], 0, 0, 0);
            acc[0][0] = __builtin_amdgcn_mfma_f32_16x16x32_bf16(a_l0, b_h0, acc[0][0], 0, 0, 0);
            acc[0][1] = __builtin_amdgcn_mfma_f32_16x16x32_bf16(a_l0, b_h1, acc[0][1], 0, 0, 0);
            acc[1][0] = __builtin_amdgcn_mfma_f32_16x16x32_bf16(a_l1, b_h0, acc[1][0], 0, 0, 0);
            acc[1][1] = __builtin_amdgcn_mfma_f32_16x16x32_bf16(a_l1, b_h1, acc[1][1], 0, 0, 0);
        }
    }

    // epilogue: h writes + si/sj partials reduced across the two wn-waves
    // via LDS (reuse Ah as float scratch; no global atomics).
    float adv[2], asv[2];
    #pragma unroll
    for (int fc = 0; fc < 2; fc++) {
        adv[fc] = a1df[hd * DD + wn * 32 + fc * 16 + lr];
        asv[fc] = a1sf[hd * DD + wn * 32 + fc * 16 + lr];
    }
    float pdv[2][4], psv[2][4];
    #pragma unroll
    for (int fr = 0; fr < 2; fr++) {
        #pragma unroll
        for (int q = 0; q < 4; q++) {
            int row = bm * 64 + wm * 32 + fr * 16 + lg * 4 + q;
            int colb = hd * 64 + wn * 32;
            hb[(size_t)row * HD + colb + lr] = f2bf(acc[fr][0][q]);
            hb[(size_t)row * HD + colb + 16 + lr] = f2bf(acc[fr][1][q]);
            float pd = acc[fr][0][q] * adv[0] + acc[fr][1][q] * adv[1];
            float ps = acc[fr][0][q] * asv[0] + acc[fr][1][q] * asv[1];
            #pragma unroll
            for (int off = 1; off < 16; off <<= 1) {
                pd += __shfl_xor(pd, off, 64);
                ps += __shfl_xor(ps, off, 64);
            }
            pdv[fr][q] = pd;
            psv[fr][q] = ps;
        }
    }
    float* sred = (float*)&Ah[0][0];  // 64 rows x {si,sj} = 512B
    __syncthreads();
    if (wn == 0 && lr == 0) {
        #pragma unroll
        for (int fr = 0; fr < 2; fr++)
            #pragma unroll
            for (int q = 0; q < 4; q++) {
                int rl = wm * 32 + fr * 16 + lg * 4 + q;
                sred[rl * 2] = pdv[fr][q];
                sred[rl * 2 + 1] = psv[fr][q];
            }
    }
    __syncthreads();
    if (wn == 1 && lr == 0) {
        #pragma unroll
        for (int fr = 0; fr < 2; fr++)
            #pragma unroll
            for (int q = 0; q < 4; q++) {
                int rl = wm * 32 + fr * 16 + lg * 4 + q;
                int row = bm * 64 + rl;
                si[hd * NN + row] = sred[rl * 2] + pdv[fr][q];
                sj[hd * NN + row] = sred[rl * 2 + 1] + psv[fr][q];
            }
    }
}

// -------- layer-1 attention: 256 thr/node, uint (2xbf16) gather -------------
__global__ __launch_bounds__(256) void l1_attn(const int* __restrict__ nbr,
                                               const int* __restrict__ deg,
                                               const unsigned short* __restrict__ hb,
                                               const float* __restrict__ si,
                                               const float* __restrict__ sj,
                                               float* __restrict__ x2) {
    int i = blockIdx.x;
    int tid = threadIdx.x;
    int wave = tid >> 6, lane = tid & 63;
    int d = deg[i];
    __shared__ int js[MAXDEG];
    __shared__ float wls[HH][MAXDEG];
    for (int k = tid; k < d; k += 256) js[k] = nbr[(size_t)i * MAXDEG + k];
    __syncthreads();

    int hd = wave * 2 + (lane >> 5);
    int l32 = lane & 31;
    float sii = si[hd * NN + i];
    const float* sjh = sj + (size_t)hd * NN;
    float m = -1e30f;
    for (int k = l32; k < d; k += 32) {
        float sc = sii + sjh[js[k]];
        sc = sc > 0.f ? sc : ALPHA * sc;
        wls[hd][k] = sc;
        m = fmaxf(m, sc);
    }
    #pragma unroll
    for (int off = 16; off; off >>= 1) m = fmaxf(m, __shfl_xor(m, off, 64));
    float s = 0.f;
    for (int k = l32; k < d; k += 32) {
        float e = expf(wls[hd][k] - m);
        wls[hd][k] = e;
        s += e;
    }
    #pragma unroll
    for (int off = 16; off; off >>= 1) s += __shfl_xor(s, off, 64);
    float inv = 1.f / fmaxf(s, 1e-30f);
    for (int k = l32; k < d; k += 32) wls[hd][k] *= inv;
    __syncthreads();

    const unsigned int* hu = (const unsigned int*)hb;
    const float* wl = wls[tid >> 5];
    float a0 = 0.f, a1 = 0.f;
    int k = 0;
    for (; k + 4 <= d; k += 4) {
        unsigned int v0 = hu[(size_t)js[k] * 256 + tid];
        unsigned int v1 = hu[(size_t)js[k + 1] * 256 + tid];
        unsigned int v2 = hu[(size_t)js[k + 2] * 256 + tid];
        unsigned int v3 = hu[(size_t)js[k + 3] * 256 + tid];
        float w0 = wl[k], w1 = wl[k + 1], w2 = wl[k + 2], w3 = wl[k + 3];
        a0 = fmaf(w0, bf2f((unsigned short)v0), a0);
        a1 = fmaf(w0, bf2f((unsigned short)(v0 >> 16)), a1);
        a0 = fmaf(w1, bf2f((unsigned short)v1), a0);
        a1 = fmaf(w1, bf2f((unsigned short)(v1 >> 16)), a1);
        a0 = fmaf(w2, bf2f((unsigned short)v2), a0);
        a1 = fmaf(w2, bf2f((unsigned short)(v2 >> 16)), a1);
        a0 = fmaf(w3, bf2f((unsigned short)v3), a0);
        a1 = fmaf(w3, bf2f((unsigned short)(v3 >> 16)), a1);
    }
    for (; k < d; k++) {
        unsigned int v = hu[(size_t)js[k] * 256 + tid];
        float w = wl[k];
        a0 = fmaf(w, bf2f((unsigned short)v), a0);
        a1 = fmaf(w, bf2f((unsigned short)(v >> 16)), a1);
    }
    float r0 = a0 > 0.f ? a0 : expm1f(a0);  // ELU fused
    float r1 = a1 > 0.f ? a1 : expm1f(a1);
    *(float2*)(x2 + (size_t)i * HD + tid * 2) = make_float2(r0, r1);
}

// ------ l2 GEMM fused: split-K tiles atomically accumulated into h2/d1/d2 ---
// Each (bm, sk) block computes a 64x64 tile over its K-slice; since h2, d1,
// d2 are linear in the partials, it reduces its own contribution directly:
// h2 += acc (f32 atomics, contiguous addrs -> L2 pipelined);
// d1/d2 += per-row dot (16-lane shuffle, one atomicAdd per row).
__global__ __launch_bounds__(256) void l2_gemm(const float* __restrict__ x2,
                                               const float* __restrict__ W2p,
                                               const float* __restrict__ a2sf,
                                               const float* __restrict__ a2df,
                                               float* __restrict__ h2,
                                               float* __restrict__ d1,
                                               float* __restrict__ d2) {
    __shared__ float As[BK][BM + 4];
    __shared__ float Bs[BK][BN + 4];
    int bm = blockIdx.x, sk = blockIdx.y;
    int tid = threadIdx.x;
    int tm = tid >> 4, tn = tid & 15;
    int m0 = tm * 4, n0 = tn * 4;
    int ar = tid >> 2, ak = (tid & 3) * 4;
    int bk = tid >> 4, bq = (tid & 15) * 4;

    const float* Ap = x2 + (size_t)(bm * BM) * FF + sk * KH2;
    const float* Bp = W2p + (size_t)(sk * KH2) * CP;

    float acc[4][4];
    #pragma unroll
    for (int r = 0; r < 4; r++)
        #pragma unroll
        for (int c = 0; c < 4; c++) acc[r][c] = 0.f;

    const float* Ar = Ap + (size_t)ar * FF;
    float4 av = *(const float4*)(Ar + ak);
    float4 bv = *(const float4*)(Bp + (size_t)bk * CP + bq);

    for (int k0 = 0; k0 < KH2; k0 += BK) {
        __syncthreads();
        As[ak + 0][ar] = av.x;
        As[ak + 1][ar] = av.y;
        As[ak + 2][ar] = av.z;
        As[ak + 3][ar] = av.w;
        *(float4*)&Bs[bk][bq] = bv;
        __syncthreads();

        int kn = (k0 + BK < KH2) ? k0 + BK : k0;
        av = *(const float4*)(Ar + kn + ak);
        bv = *(const float4*)(Bp + (size_t)(kn + bk) * CP + bq);

        #pragma unroll
        for (int k = 0; k < BK; k++) {
            float4 a = *(const float4*)&As[k][m0];
            float4 b = *(const float4*)&Bs[k][n0];
            acc[0][0] = fmaf(a.x, b.x, acc[0][0]);
            acc[0][1] = fmaf(a.x, b.y, acc[0][1]);
            acc[0][2] = fmaf(a.x, b.z, acc[0][2]);
            acc[0][3] = fmaf(a.x, b.w, acc[0][3]);
            acc[1][0] = fmaf(a.y, b.x, acc[1][0]);
            acc[1][1] = fmaf(a.y, b.y, acc[1][1]);
            acc[1][2] = fmaf(a.y, b.z, acc[1][2]);
            acc[1][3] = fmaf(a.y, b.w, acc[1][3]);
            acc[2][0] = fmaf(a.z, b.x, acc[2][0]);
            acc[2][1] = fmaf(a.z, b.y, acc[2][1]);
            acc[2][2] = fmaf(a.z, b.z, acc[2][2]);
            acc[2][3] = fmaf(a.z, b.w, acc[2][3]);
            acc[3][0] = fmaf(a.w, b.x, acc[3][0]);
            acc[3][1] = fmaf(a.w, b.y, acc[3][1]);
            acc[3][2] = fmaf(a.w, b.z, acc[3][2]);
            acc[3][3] = fmaf(a.w, b.w, acc[3][3]);
        }
    }

    float ad[4], as[4];
    #pragma unroll
    for (int q = 0; q < 4; q++) {
        int c = n0 + q;
        ad[q] = (c < CC) ? a2df[c] : 0.f;
        as[q] = (c < CC) ? a2sf[c] : 0.f;
    }
    #pragma unroll
    for (int r = 0; r < 4; r++) {
        int row = bm * BM + m0 + r;
        float pd = acc[r][0] * ad[0] + acc[r][1] * ad[1]
                 + acc[r][2] * ad[2] + acc[r][3] * ad[3];
        float ps = acc[r][0] * as[0] + acc[r][1] * as[1]
                 + acc[r][2] * as[2] + acc[r][3] * as[3];
        #pragma unroll
        for (int off = 1; off < 16; off <<= 1) {
            pd += __shfl_xor(pd, off, 64);
            ps += __shfl_xor(ps, off, 64);
        }
        if (tn == 0) {
            atomicAdd(&d1[row], pd);
            atomicAdd(&d2[row], ps);
        }
        #pragma unroll
        for (int q = 0; q < 4; q++) {
            int c = n0 + q;
            if (c < CC) atomicAdd(&h2[(size_t)row * CC + c], acc[r][q]);
        }
    }
}

// -------- layer-2 attention: 4 nodes per 256-thread block, wave = node ------
__global__ __launch_bounds__(256) void l2_attn(const int* __restrict__ nbr,
                                               const int* __restrict__ deg,
                                               const float* __restrict__ h2,
                                               const float* __restrict__ d1,
                                               const float* __restrict__ d2,
                                               float* __restrict__ out) {
    int w = threadIdx.x >> 6, lane = threadIdx.x & 63;
    int i = blockIdx.x * 4 + w;
    int d = deg[i];
    __shared__ int js[4][MAXDEG];
    __shared__ float wls[4][MAXDEG];
    for (int k = lane; k < d; k += 64) js[w][k] = nbr[(size_t)i * MAXDEG + k];

    float sii = d1[i];
    float m = -1e30f;
    for (int k = lane; k < d; k += 64) {
        float sc = sii + d2[js[w][k]];
        sc = sc > 0.f ? sc : ALPHA * sc;
        wls[w][k] = sc;
        m = fmaxf(m, sc);
    }
    m = wave_max(m);
    float s = 0.f;
    for (int k = lane; k < d; k += 64) {
        float e = expf(wls[w][k] - m);
        wls[w][k] = e;
        s += e;
    }
    s = fmaxf(wave_sum(s), 1e-30f);

    int c = lane;
    if (c < CC) {
        float acc = 0.f;
        int k = 0;
        for (; k + 4 <= d; k += 4) {
            float v0 = h2[(size_t)js[w][k] * CC + c];
            float v1 = h2[(size_t)js[w][k + 1] * CC + c];
            float v2 = h2[(size_t)js[w][k + 2] * CC + c];
            float v3 = h2[(size_t)js[w][k + 3] * CC + c];
            acc = fmaf(wls[w][k], v0, acc);
            acc = fmaf(wls[w][k + 1], v1, acc);
            acc = fmaf(wls[w][k + 2], v2, acc);
            acc = fmaf(wls[w][k + 3], v3, acc);
        }
        for (; k < d; k++)
            acc = fmaf(wls[w][k], h2[(size_t)js[w][k] * CC + c], acc);
        out[(size_t)i * CC + c] = acc / s;
    }
}

extern "C" void kernel_launch(void* const* d_in, const int* in_sizes, int n_in,
                              void* d_out, int out_size, void* d_ws, size_t ws_size,
                              hipStream_t stream) {
    const void* x   = d_in[0];
    const unsigned char* adj = (const unsigned char*)d_in[1];
    const void* W1  = d_in[2];
    const void* a1s = d_in[3];  // a1_src
    const void* a1d = d_in[4];  // a1_dst
    const void* W2  = d_in[5];
    const void* a2s = d_in[6];
    const void* a2d = d_in[7];

    char* ws = (char*)d_ws;
    int*   nbr   = (int*)(ws + 0);                        // 2,097,152
    int*   deg   = (int*)(ws + 2097152);                  // 16,384
    float* si    = (float*)(ws + 2113536);                // 131,072
    float* sj    = (float*)(ws + 2244608);                // 131,072
    unsigned short* W1bth = (unsigned short*)(ws + 2375680);  // 524,288
    unsigned short* W1btl = (unsigned short*)(ws + 2899968);  // 524,288
    float* W2p   = (float*)(ws + 3424256);                // 131,072
    float* a1sf  = (float*)(ws + 3555328);                // 2,048
    float* a1df  = (float*)(ws + 3557376);                // 2,048
    float* a2sf  = (float*)(ws + 3559424);                // 256
    float* a2df  = (float*)(ws + 3559680);                // 256
    unsigned short* hb = (unsigned short*)(ws + 3559936); // 4,194,304 [N][H*D] bf16
    float* x2    = (float*)(ws + 7754240);                // 8,388,608
    float* h2    = (float*)(ws + 16142848);               // 655,360
    float* d1    = (float*)(ws + 16798208);               // 16,384
    float* d2    = (float*)(ws + 16814592);               // 16,384
    // total ~16.8 MB

    // prep grid: 4096 nbr rows + 64 W1-transpose + small/zero section
    const int nSmall = HD * CP + 2 * HD + 2 * CC + NN * CC + 2 * NN;  // 205,904
    const int prepGrid = NN + 64 + (nSmall + 255) / 256;
    hipLaunchKernelGGL(prep, dim3(prepGrid), dim3(256), 0, stream,
                       adj, x, W1, W2, a1s, a1d, a2s, a2d,
                       nbr, deg, W1bth, W1btl, W2p, a1sf, a1df, a2sf, a2df,
                       h2, d1, d2);

    hipLaunchKernelGGL(l1_gemm, dim3(NN / 64, HH), dim3(256), 0, stream,
                       x, W1bth, W1btl, a1sf, a1df, hb, si, sj);
    hipLaunchKernelGGL(l1_attn, dim3(NN), dim3(256), 0, stream,
                       nbr, deg, hb, si, sj, x2);
    hipLaunchKernelGGL(l2_gemm, dim3(NN / BM, SK2), dim3(256), 0, stream,
                       x2, W2p, a2sf, a2df, h2, d1, d2);
    hipLaunchKernelGGL(l2_attn, dim3(NN / 4), dim3(256), 0, stream,
                       nbr, deg, h2, d1, d2, (float*)d_out);
}

// Round 15
// 160.483 us; speedup vs baseline: 1.1066x; 1.1066x over previous
//
#include <hip/hip_runtime.h>

#define NN 4096
#define FF 512
#define DD 64
#define HH 8
#define CC 40
#define HD (HH * DD)   // 512
#define CP 64          // padded class dim
#define MAXDEG 128
#define ALPHA 0.2f

// f32 GEMM tiling (l2)
#define BM 64
#define BN 64
#define BK 16
#define SK2 8
#define KH2 (FF / SK2) // 64 per split

typedef __attribute__((ext_vector_type(8))) short bf16x8;
typedef __attribute__((ext_vector_type(4))) float f32x4;

__device__ __forceinline__ float bf2f(unsigned short u) {
    union { unsigned int i; float f; } v;
    v.i = ((unsigned int)u) << 16;
    return v.f;
}

__device__ __forceinline__ unsigned short f2bf(float f) {
    union { float f; unsigned int u; } v;
    v.f = f;
    unsigned int r = v.u + 0x7fffu + ((v.u >> 16) & 1u);  // RNE
    return (unsigned short)(r >> 16);
}

__device__ __forceinline__ float wave_sum(float v) {
    #pragma unroll
    for (int off = 32; off; off >>= 1) v += __shfl_xor(v, off, 64);
    return v;
}

__device__ __forceinline__ float wave_max(float v) {
    #pragma unroll
    for (int off = 32; off; off >>= 1) v = fmaxf(v, __shfl_xor(v, off, 64));
    return v;
}

__device__ __forceinline__ float read_f(const void* src, int i, int isBf16) {
    if (isBf16) return bf2f(((const unsigned short*)src)[i]);
    return ((const float*)src)[i];
}

// Inline x-dtype sniff: every block reads the SAME x[0:1024] words (4KB,
// L2-hit) -> all blocks reach the same verdict deterministically.
__device__ __forceinline__ int sniff_x(const void* xraw, int tid, int* fS) {
    if (tid == 0) *fS = 1;
    __syncthreads();
    int bad = 0;
    const unsigned int* xw = (const unsigned int*)xraw;
    #pragma unroll
    for (int q = 0; q < 4; q++) {
        unsigned int w = xw[(tid & 255) * 4 + q];
        unsigned int e0 = (w >> 7) & 0xffu;
        unsigned int e1 = (w >> 23) & 0xffu;
        if (e0 >= 0x90u || e1 >= 0x90u) bad = 1;
    }
    if (bad) *fS = 0;
    __syncthreads();
    return *fS;
}

// ---------------- prep: build_nbr + all conversions in ONE launch -----------
// NOTE (R14 post-mortem): do NOT fuse the l2 split-K reduction into l2_gemm
// via global atomicAdd — cross-XCD f32 atomics resolve at the fabric
// coherence point (per-XCD L2s non-coherent) and cost +16.5 us vs the
// L2-resident Cp2 partials round-trip used here.
__global__ __launch_bounds__(256) void prep(const unsigned char* __restrict__ adj,
                                            const void* __restrict__ x,
                                            const void* __restrict__ W1,
                                            const void* __restrict__ W2,
                                            const void* __restrict__ a1s,
                                            const void* __restrict__ a1d,
                                            const void* __restrict__ a2s,
                                            const void* __restrict__ a2d,
                                            int* __restrict__ nbr,
                                            int* __restrict__ deg,
                                            unsigned short* __restrict__ W1bth,
                                            unsigned short* __restrict__ W1btl,
                                            float* __restrict__ W2p,
                                            float* __restrict__ a1sf,
                                            float* __restrict__ a1df,
                                            float* __restrict__ a2sf,
                                            float* __restrict__ a2df) {
    __shared__ int cnt;
    __shared__ int fS;
    int t = threadIdx.x;
    int blk = blockIdx.x;

    if (blk < NN) {
        // ---- build_nbr path; adj elem-size sniff: byte t*(NN+1) (valid in
        // both layouts). Byte-bool: diagonal -> all 1. Int32: t%4!=0 hits a
        // zero byte-lane of a 0/1 word -> 0.
        if (t == 0) { cnt = 0; fS = 1; }
        __syncthreads();
        if (adj[(size_t)t * (NN + 1)] == 0) fS = 0;  // benign race
        __syncthreads();
        int isByte = fS;
        int i = blk;
        if (isByte) {
            uint4 v = ((const uint4*)(adj + (size_t)i * NN))[t];
            unsigned int u[4] = { v.x, v.y, v.z, v.w };
            int base = t * 16;
            #pragma unroll
            for (int q = 0; q < 4; q++) {
                #pragma unroll
                for (int b = 0; b < 4; b++) {
                    if ((u[q] >> (8 * b)) & 0xffu) {
                        int p = atomicAdd(&cnt, 1);
                        if (p < MAXDEG) nbr[(size_t)i * MAXDEG + p] = base + q * 4 + b;
                    }
                }
            }
        } else {
            const int4* row = (const int4*)((const int*)adj + (size_t)i * NN);
            #pragma unroll
            for (int q = 0; q < 4; q++) {
                int idx4 = q * 256 + t;
                int4 v = row[idx4];
                int base = idx4 * 4;
                if (v.x) { int p = atomicAdd(&cnt, 1); if (p < MAXDEG) nbr[(size_t)i * MAXDEG + p] = base; }
                if (v.y) { int p = atomicAdd(&cnt, 1); if (p < MAXDEG) nbr[(size_t)i * MAXDEG + p] = base + 1; }
                if (v.z) { int p = atomicAdd(&cnt, 1); if (p < MAXDEG) nbr[(size_t)i * MAXDEG + p] = base + 2; }
                if (v.w) { int p = atomicAdd(&cnt, 1); if (p < MAXDEG) nbr[(size_t)i * MAXDEG + p] = base + 3; }
            }
        }
        __syncthreads();
        if (t == 0) deg[i] = min(cnt, MAXDEG);
        return;
    }

    int bf = sniff_x(x, t, &fS);

    if (blk < NN + 64) {
        // ---- W1 transpose path: thread owns 16 consecutive OUTPUT elems
        // (32B coalesced store per array); reads are stride-DD, L2-resident.
        int b = blk - NN;                       // 0..63
        int ob = b * 4096 + t * 16;             // output elem base (262,144 tot)
        int row = ob >> 9;                      // hd*64 + d
        int f0 = ob & 511;
        int hd = row >> 6, d = row & 63;
        unsigned short hi[16], lo[16];
        #pragma unroll
        for (int q = 0; q < 16; q++) {
            float v = read_f(W1, (hd * FF + f0 + q) * DD + d, bf);
            unsigned short h16 = f2bf(v);
            hi[q] = h16;
            lo[q] = f2bf(v - bf2f(h16));
        }
        #pragma unroll
        for (int q = 0; q < 16; q++) {
            W1bth[(size_t)row * FF + f0 + q] = hi[q];
            W1btl[(size_t)row * FF + f0 + q] = lo[q];
        }
        return;
    }

    // ---- small tensors: W2p (zero-padded), a-vectors
    int i = (blk - NN - 64) * 256 + t;
    const int nW2p = HD * CP;          // 32,768
    const int nA1 = HD;                // 512
    if (i < nW2p) {
        int k = i / CP, c = i % CP;
        W2p[i] = (c < CC) ? read_f(W2, k * CC + c, bf) : 0.f;
        return;
    }
    i -= nW2p;
    if (i < nA1) { a1sf[i] = read_f(a1s, i, bf); return; }
    i -= nA1;
    if (i < nA1) { a1df[i] = read_f(a1d, i, bf); return; }
    i -= nA1;
    if (i < CC) { a2sf[i] = read_f(a2s, i, bf); return; }
    i -= CC;
    if (i < CC) { a2df[i] = read_f(a2d, i, bf); return; }
}

// ------ l1 GEMM via MFMA bf16x3, native x; si/sj via LDS (no atomics) -------
__global__ __launch_bounds__(256) void l1_gemm(const void* __restrict__ xraw,
                                               const unsigned short* __restrict__ W1bth,
                                               const unsigned short* __restrict__ W1btl,
                                               const float* __restrict__ a1sf,
                                               const float* __restrict__ a1df,
                                               unsigned short* __restrict__ hb,
                                               float* __restrict__ si,
                                               float* __restrict__ sj) {
    __shared__ __align__(16) unsigned short Ah[64][40];
    __shared__ __align__(16) unsigned short Al[64][40];
    __shared__ __align__(16) unsigned short Bh[64][40];
    __shared__ __align__(16) unsigned short Bl[64][40];
    __shared__ int fS;

    int bm = blockIdx.x, hd = blockIdx.y;
    int tid = threadIdx.x;
    int isBf16 = sniff_x(xraw, tid, &fS);

    int wave = tid >> 6, lane = tid & 63;
    int wm = wave >> 1, wn = wave & 1;
    int lr = lane & 15, lg = lane >> 4;
    int srow = tid >> 2;
    int sseg = (tid & 3) * 8;

    const unsigned short* wAp = W1bth + (size_t)(hd * 64 + srow) * FF + sseg;
    const unsigned short* wBp = W1btl + (size_t)(hd * 64 + srow) * FF + sseg;

    f32x4 acc[2][2];
    #pragma unroll
    for (int r = 0; r < 2; r++)
        #pragma unroll
        for (int c = 0; c < 2; c++) acc[r][c] = (f32x4){0.f, 0.f, 0.f, 0.f};

    if (isBf16) {
        const unsigned short* xp = (const unsigned short*)xraw
                                 + (size_t)(bm * 64 + srow) * FF + sseg;
        uint4 ra = *(const uint4*)xp;
        uint4 rb = *(const uint4*)wAp;
        for (int kk = 0; kk < FF; kk += 32) {
            __syncthreads();
            *(uint4*)&Ah[srow][sseg] = ra;
            *(uint4*)&Bh[srow][sseg] = rb;
            __syncthreads();
            int kn = (kk + 32 < FF) ? kk + 32 : kk;
            ra = *(const uint4*)(xp + kn);
            rb = *(const uint4*)(wAp + kn);
            bf16x8 a0 = *(const bf16x8*)&Ah[wm * 32 + lr][lg * 8];
            bf16x8 a1 = *(const bf16x8*)&Ah[wm * 32 + 16 + lr][lg * 8];
            bf16x8 b0 = *(const bf16x8*)&Bh[wn * 32 + lr][lg * 8];
            bf16x8 b1 = *(const bf16x8*)&Bh[wn * 32 + 16 + lr][lg * 8];
            acc[0][0] = __builtin_amdgcn_mfma_f32_16x16x32_bf16(a0, b0, acc[0][0], 0, 0, 0);
            acc[0][1] = __builtin_amdgcn_mfma_f32_16x16x32_bf16(a0, b1, acc[0][1], 0, 0, 0);
            acc[1][0] = __builtin_amdgcn_mfma_f32_16x16x32_bf16(a1, b0, acc[1][0], 0, 0, 0);
            acc[1][1] = __builtin_amdgcn_mfma_f32_16x16x32_bf16(a1, b1, acc[1][1], 0, 0, 0);
        }
    } else {
        const float* xp = (const float*)xraw + (size_t)(bm * 64 + srow) * FF + sseg;
        float4 ra0 = *(const float4*)xp;
        float4 ra1 = *(const float4*)(xp + 4);
        uint4 rbh = *(const uint4*)wAp;
        uint4 rbl = *(const uint4*)wBp;
        for (int kk = 0; kk < FF; kk += 32) {
            __syncthreads();
            union { unsigned short s[8]; uint4 v; } uh, ul;
            float fv[8] = { ra0.x, ra0.y, ra0.z, ra0.w, ra1.x, ra1.y, ra1.z, ra1.w };
            #pragma unroll
            for (int q = 0; q < 8; q++) {
                unsigned short h16 = f2bf(fv[q]);
                uh.s[q] = h16;
                ul.s[q] = f2bf(fv[q] - bf2f(h16));
            }
            *(uint4*)&Ah[srow][sseg] = uh.v;
            *(uint4*)&Al[srow][sseg] = ul.v;
            *(uint4*)&Bh[srow][sseg] = rbh;
            *(uint4*)&Bl[srow][sseg] = rbl;
            __syncthreads();
            int kn = (kk + 32 < FF) ? kk + 32 : kk;
            ra0 = *(const float4*)(xp + kn);
            ra1 = *(const float4*)(xp + kn + 4);
            rbh = *(const uint4*)(wAp + kn);
            rbl = *(const uint4*)(wBp + kn);

            bf16x8 a_h0 = *(const bf16x8*)&Ah[wm * 32 + lr][lg * 8];
            bf16x8 a_h1 = *(const bf16x8*)&Ah[wm * 32 + 16 + lr][lg * 8];
            bf16x8 a_l0 = *(const bf16x8*)&Al[wm * 32 + lr][lg * 8];
            bf16x8 a_l1 = *(const bf16x8*)&Al[wm * 32 + 16 + lr][lg * 8];
            bf16x8 b_h0 = *(const bf16x8*)&Bh[wn * 32 + lr][lg * 8];
            bf16x8 b_h1 = *(const bf16x8*)&Bh[wn * 32 + 16 + lr][lg * 8];
            bf16x8 b_l0 = *(const bf16x8*)&Bl[wn * 32 + lr][lg * 8];
            bf16x8 b_l1 = *(const bf16x8*)&Bl[wn * 32 + 16 + lr][lg * 8];

            acc[0][0] = __builtin_amdgcn_mfma_f32_16x16x32_bf16(a_h0, b_h0, acc[0][0], 0, 0, 0);
            acc[0][1] = __builtin_amdgcn_mfma_f32_16x16x32_bf16(a_h0, b_h1, acc[0][1], 0, 0, 0);
            acc[1][0] = __builtin_amdgcn_mfma_f32_16x16x32_bf16(a_h1, b_h0, acc[1][0], 0, 0, 0);
            acc[1][1] = __builtin_amdgcn_mfma_f32_16x16x32_bf16(a_h1, b_h1, acc[1][1], 0, 0, 0);
            acc[0][0] = __builtin_amdgcn_mfma_f32_16x16x32_bf16(a_h0, b_l0, acc[0][0], 0, 0, 0);
            acc[0][1] = __builtin_amdgcn_mfma_f32_16x16x32_bf16(a_h0, b_l1, acc[0][1], 0, 0, 0);
            acc[1][0] = __builtin_amdgcn_mfma_f32_16x16x32_bf16(a_h1, b_l0, acc[1][0], 0, 0, 0);
            acc[1][1] = __builtin_amdgcn_mfma_f32_16x16x32_bf16(a_h1, b_l1, acc[1][1], 0, 0, 0);
            acc[0][0] = __builtin_amdgcn_mfma_f32_16x16x32_bf16(a_l0, b_h0, acc[0][0], 0, 0, 0);
            acc[0][1] = __builtin_amdgcn_mfma_f32_16x16x32_bf16(a_l0, b_h1, acc[0][1], 0, 0, 0);
            acc[1][0] = __builtin_amdgcn_mfma_f32_16x16x32_bf16(a_l1, b_h0, acc[1][0], 0, 0, 0);
            acc[1][1] = __builtin_amdgcn_mfma_f32_16x16x32_bf16(a_l1, b_h1, acc[1][1], 0, 0, 0);
        }
    }

    // epilogue: h writes + si/sj partials reduced across the two wn-waves
    // via LDS (reuse Ah as float scratch; no global atomics).
    float adv[2], asv[2];
    #pragma unroll
    for (int fc = 0; fc < 2; fc++) {
        adv[fc] = a1df[hd * DD + wn * 32 + fc * 16 + lr];
        asv[fc] = a1sf[hd * DD + wn * 32 + fc * 16 + lr];
    }
    float pdv[2][4], psv[2][4];
    #pragma unroll
    for (int fr = 0; fr < 2; fr++) {
        #pragma unroll
        for (int q = 0; q < 4; q++) {
            int row = bm * 64 + wm * 32 + fr * 16 + lg * 4 + q;
            int colb = hd * 64 + wn * 32;
            hb[(size_t)row * HD + colb + lr] = f2bf(acc[fr][0][q]);
            hb[(size_t)row * HD + colb + 16 + lr] = f2bf(acc[fr][1][q]);
            float pd = acc[fr][0][q] * adv[0] + acc[fr][1][q] * adv[1];
            float ps = acc[fr][0][q] * asv[0] + acc[fr][1][q] * asv[1];
            #pragma unroll
            for (int off = 1; off < 16; off <<= 1) {
                pd += __shfl_xor(pd, off, 64);
                ps += __shfl_xor(ps, off, 64);
            }
            pdv[fr][q] = pd;
            psv[fr][q] = ps;
        }
    }
    float* sred = (float*)&Ah[0][0];  // 64 rows x {si,sj} = 512B
    __syncthreads();
    if (wn == 0 && lr == 0) {
        #pragma unroll
        for (int fr = 0; fr < 2; fr++)
            #pragma unroll
            for (int q = 0; q < 4; q++) {
                int rl = wm * 32 + fr * 16 + lg * 4 + q;
                sred[rl * 2] = pdv[fr][q];
                sred[rl * 2 + 1] = psv[fr][q];
            }
    }
    __syncthreads();
    if (wn == 1 && lr == 0) {
        #pragma unroll
        for (int fr = 0; fr < 2; fr++)
            #pragma unroll
            for (int q = 0; q < 4; q++) {
                int rl = wm * 32 + fr * 16 + lg * 4 + q;
                int row = bm * 64 + rl;
                si[hd * NN + row] = sred[rl * 2] + pdv[fr][q];
                sj[hd * NN + row] = sred[rl * 2 + 1] + psv[fr][q];
            }
    }
}

// -------- layer-1 attention: 256 thr/node, uint (2xbf16) gather -------------
__global__ __launch_bounds__(256) void l1_attn(const int* __restrict__ nbr,
                                               const int* __restrict__ deg,
                                               const unsigned short* __restrict__ hb,
                                               const float* __restrict__ si,
                                               const float* __restrict__ sj,
                                               float* __restrict__ x2) {
    int i = blockIdx.x;
    int tid = threadIdx.x;
    int wave = tid >> 6, lane = tid & 63;
    int d = deg[i];
    __shared__ int js[MAXDEG];
    __shared__ float wls[HH][MAXDEG];
    for (int k = tid; k < d; k += 256) js[k] = nbr[(size_t)i * MAXDEG + k];
    __syncthreads();

    int hd = wave * 2 + (lane >> 5);
    int l32 = lane & 31;
    float sii = si[hd * NN + i];
    const float* sjh = sj + (size_t)hd * NN;
    float m = -1e30f;
    for (int k = l32; k < d; k += 32) {
        float sc = sii + sjh[js[k]];
        sc = sc > 0.f ? sc : ALPHA * sc;
        wls[hd][k] = sc;
        m = fmaxf(m, sc);
    }
    #pragma unroll
    for (int off = 16; off; off >>= 1) m = fmaxf(m, __shfl_xor(m, off, 64));
    float s = 0.f;
    for (int k = l32; k < d; k += 32) {
        float e = expf(wls[hd][k] - m);
        wls[hd][k] = e;
        s += e;
    }
    #pragma unroll
    for (int off = 16; off; off >>= 1) s += __shfl_xor(s, off, 64);
    float inv = 1.f / fmaxf(s, 1e-30f);
    for (int k = l32; k < d; k += 32) wls[hd][k] *= inv;
    __syncthreads();

    const unsigned int* hu = (const unsigned int*)hb;
    const float* wl = wls[tid >> 5];
    float a0 = 0.f, a1 = 0.f;
    int k = 0;
    for (; k + 4 <= d; k += 4) {
        unsigned int v0 = hu[(size_t)js[k] * 256 + tid];
        unsigned int v1 = hu[(size_t)js[k + 1] * 256 + tid];
        unsigned int v2 = hu[(size_t)js[k + 2] * 256 + tid];
        unsigned int v3 = hu[(size_t)js[k + 3] * 256 + tid];
        float w0 = wl[k], w1 = wl[k + 1], w2 = wl[k + 2], w3 = wl[k + 3];
        a0 = fmaf(w0, bf2f((unsigned short)v0), a0);
        a1 = fmaf(w0, bf2f((unsigned short)(v0 >> 16)), a1);
        a0 = fmaf(w1, bf2f((unsigned short)v1), a0);
        a1 = fmaf(w1, bf2f((unsigned short)(v1 >> 16)), a1);
        a0 = fmaf(w2, bf2f((unsigned short)v2), a0);
        a1 = fmaf(w2, bf2f((unsigned short)(v2 >> 16)), a1);
        a0 = fmaf(w3, bf2f((unsigned short)v3), a0);
        a1 = fmaf(w3, bf2f((unsigned short)(v3 >> 16)), a1);
    }
    for (; k < d; k++) {
        unsigned int v = hu[(size_t)js[k] * 256 + tid];
        float w = wl[k];
        a0 = fmaf(w, bf2f((unsigned short)v), a0);
        a1 = fmaf(w, bf2f((unsigned short)(v >> 16)), a1);
    }
    float r0 = a0 > 0.f ? a0 : expm1f(a0);  // ELU fused
    float r1 = a1 > 0.f ? a1 : expm1f(a1);
    *(float2*)(x2 + (size_t)i * HD + tid * 2) = make_float2(r0, r1);
}

// ------ generic LDS-tiled split-K GEMM body (l2) ----------------------------
template <int KHs, int Nb>
__device__ __forceinline__ void gemm_body(const float* __restrict__ Ap,
                                          const float* __restrict__ Bp,
                                          float* __restrict__ Co,
                                          int tid, int bm) {
    __shared__ float As[BK][BM + 4];
    __shared__ float Bs[BK][BN + 4];
    int tm = tid >> 4, tn = tid & 15;
    int m0 = tm * 4, n0 = tn * 4;
    int ar = tid >> 2, ak = (tid & 3) * 4;
    int bk = tid >> 4, bq = (tid & 15) * 4;

    float acc[4][4];
    #pragma unroll
    for (int r = 0; r < 4; r++)
        #pragma unroll
        for (int c = 0; c < 4; c++) acc[r][c] = 0.f;

    const float* Ar = Ap + (size_t)ar * FF;
    float4 av = *(const float4*)(Ar + ak);
    float4 bv = *(const float4*)(Bp + (size_t)bk * Nb + bq);

    for (int k0 = 0; k0 < KHs; k0 += BK) {
        __syncthreads();
        As[ak + 0][ar] = av.x;
        As[ak + 1][ar] = av.y;
        As[ak + 2][ar] = av.z;
        As[ak + 3][ar] = av.w;
        *(float4*)&Bs[bk][bq] = bv;
        __syncthreads();

        int kn = (k0 + BK < KHs) ? k0 + BK : k0;
        av = *(const float4*)(Ar + kn + ak);
        bv = *(const float4*)(Bp + (size_t)(kn + bk) * Nb + bq);

        #pragma unroll
        for (int k = 0; k < BK; k++) {
            float4 a = *(const float4*)&As[k][m0];
            float4 b = *(const float4*)&Bs[k][n0];
            acc[0][0] = fmaf(a.x, b.x, acc[0][0]);
            acc[0][1] = fmaf(a.x, b.y, acc[0][1]);
            acc[0][2] = fmaf(a.x, b.z, acc[0][2]);
            acc[0][3] = fmaf(a.x, b.w, acc[0][3]);
            acc[1][0] = fmaf(a.y, b.x, acc[1][0]);
            acc[1][1] = fmaf(a.y, b.y, acc[1][1]);
            acc[1][2] = fmaf(a.y, b.z, acc[1][2]);
            acc[1][3] = fmaf(a.y, b.w, acc[1][3]);
            acc[2][0] = fmaf(a.z, b.x, acc[2][0]);
            acc[2][1] = fmaf(a.z, b.y, acc[2][1]);
            acc[2][2] = fmaf(a.z, b.z, acc[2][2]);
            acc[2][3] = fmaf(a.z, b.w, acc[2][3]);
            acc[3][0] = fmaf(a.w, b.x, acc[3][0]);
            acc[3][1] = fmaf(a.w, b.y, acc[3][1]);
            acc[3][2] = fmaf(a.w, b.z, acc[3][2]);
            acc[3][3] = fmaf(a.w, b.w, acc[3][3]);
        }
    }

    #pragma unroll
    for (int r = 0; r < 4; r++) {
        float4 v = make_float4(acc[r][0], acc[r][1], acc[r][2], acc[r][3]);
        *(float4*)(Co + (size_t)(bm * BM + m0 + r) * Nb + n0) = v;
    }
}

// ------ l2 GEMM: Cp2[sk] = x2 @ W2p  (N = 64 padded) ------------------------
__global__ __launch_bounds__(256) void l2_gemm(const float* __restrict__ x2,
                                               const float* __restrict__ W2p,
                                               float* __restrict__ Cp2) {
    int bm = blockIdx.x, sk = blockIdx.z;
    gemm_body<KH2, CP>(x2 + (size_t)bm * BM * FF + sk * KH2,
                       W2p + (size_t)(sk * KH2) * CP,
                       Cp2 + (size_t)sk * NN * CP,
                       threadIdx.x, bm);
}

// ------ l2 post: h2 = sum_sk Cp2[sk], d1/d2 wave reductions -----------------
__global__ __launch_bounds__(64) void l2_post(const float* __restrict__ Cp2,
                                              const float* __restrict__ a2sf,
                                              const float* __restrict__ a2df,
                                              float* __restrict__ h2,
                                              float* __restrict__ d1,
                                              float* __restrict__ d2) {
    int n = blockIdx.x, c = threadIdx.x;
    float v = 0.f;
    #pragma unroll
    for (int sk = 0; sk < SK2; sk++)
        v += Cp2[(size_t)sk * NN * CP + (size_t)n * CP + c];
    if (c < CC) h2[(size_t)n * CC + c] = v;
    float pd = wave_sum((c < CC) ? v * a2df[c] : 0.f);
    float ps = wave_sum((c < CC) ? v * a2sf[c] : 0.f);
    if (c == 0) {
        d1[n] = pd;
        d2[n] = ps;
    }
}

// -------- layer-2 attention: 4 nodes per 256-thread block, wave = node ------
__global__ __launch_bounds__(256) void l2_attn(const int* __restrict__ nbr,
                                               const int* __restrict__ deg,
                                               const float* __restrict__ h2,
                                               const float* __restrict__ d1,
                                               const float* __restrict__ d2,
                                               float* __restrict__ out) {
    int w = threadIdx.x >> 6, lane = threadIdx.x & 63;
    int i = blockIdx.x * 4 + w;
    int d = deg[i];
    __shared__ int js[4][MAXDEG];
    __shared__ float wls[4][MAXDEG];
    for (int k = lane; k < d; k += 64) js[w][k] = nbr[(size_t)i * MAXDEG + k];

    float sii = d1[i];
    float m = -1e30f;
    for (int k = lane; k < d; k += 64) {
        float sc = sii + d2[js[w][k]];
        sc = sc > 0.f ? sc : ALPHA * sc;
        wls[w][k] = sc;
        m = fmaxf(m, sc);
    }
    m = wave_max(m);
    float s = 0.f;
    for (int k = lane; k < d; k += 64) {
        float e = expf(wls[w][k] - m);
        wls[w][k] = e;
        s += e;
    }
    s = fmaxf(wave_sum(s), 1e-30f);

    int c = lane;
    if (c < CC) {
        float acc = 0.f;
        int k = 0;
        for (; k + 4 <= d; k += 4) {
            float v0 = h2[(size_t)js[w][k] * CC + c];
            float v1 = h2[(size_t)js[w][k + 1] * CC + c];
            float v2 = h2[(size_t)js[w][k + 2] * CC + c];
            float v3 = h2[(size_t)js[w][k + 3] * CC + c];
            acc = fmaf(wls[w][k], v0, acc);
            acc = fmaf(wls[w][k + 1], v1, acc);
            acc = fmaf(wls[w][k + 2], v2, acc);
            acc = fmaf(wls[w][k + 3], v3, acc);
        }
        for (; k < d; k++)
            acc = fmaf(wls[w][k], h2[(size_t)js[w][k] * CC + c], acc);
        out[(size_t)i * CC + c] = acc / s;
    }
}

extern "C" void kernel_launch(void* const* d_in, const int* in_sizes, int n_in,
                              void* d_out, int out_size, void* d_ws, size_t ws_size,
                              hipStream_t stream) {
    const void* x   = d_in[0];
    const unsigned char* adj = (const unsigned char*)d_in[1];
    const void* W1  = d_in[2];
    const void* a1s = d_in[3];  // a1_src
    const void* a1d = d_in[4];  // a1_dst
    const void* W2  = d_in[5];
    const void* a2s = d_in[6];
    const void* a2d = d_in[7];

    char* ws = (char*)d_ws;
    int*   nbr   = (int*)(ws + 0);                        // 2,097,152
    int*   deg   = (int*)(ws + 2097152);                  // 16,384
    float* si    = (float*)(ws + 2113536);                // 131,072
    float* sj    = (float*)(ws + 2244608);                // 131,072
    unsigned short* W1bth = (unsigned short*)(ws + 2375680);  // 524,288
    unsigned short* W1btl = (unsigned short*)(ws + 2899968);  // 524,288
    float* W2p   = (float*)(ws + 3424256);                // 131,072
    float* a1sf  = (float*)(ws + 3555328);                // 2,048
    float* a1df  = (float*)(ws + 3557376);                // 2,048
    float* a2sf  = (float*)(ws + 3559424);                // 256
    float* a2df  = (float*)(ws + 3559680);                // 256
    unsigned short* hb = (unsigned short*)(ws + 3559936); // 4,194,304 [N][H*D] bf16
    float* x2    = (float*)(ws + 7754240);                // 8,388,608
    float* h2    = (float*)(ws + 16142848);               // 655,360
    float* d1    = (float*)(ws + 16798208);               // 16,384
    float* d2    = (float*)(ws + 16814592);               // 16,384
    float* Cp2   = (float*)(ws + 16830976);               // 8,388,608
    // total ~25.2 MB

    // prep grid: 4096 nbr rows + 64 W1-transpose blocks + 133 small blocks
    const int nSmall = HD * CP + 2 * HD + 2 * CC;  // 33,872
    const int prepGrid = NN + 64 + (nSmall + 255) / 256;
    hipLaunchKernelGGL(prep, dim3(prepGrid), dim3(256), 0, stream,
                       adj, x, W1, W2, a1s, a1d, a2s, a2d,
                       nbr, deg, W1bth, W1btl, W2p, a1sf, a1df, a2sf, a2df);

    hipLaunchKernelGGL(l1_gemm, dim3(NN / 64, HH), dim3(256), 0, stream,
                       x, W1bth, W1btl, a1sf, a1df, hb, si, sj);
    hipLaunchKernelGGL(l1_attn, dim3(NN), dim3(256), 0, stream,
                       nbr, deg, hb, si, sj, x2);
    hipLaunchKernelGGL(l2_gemm, dim3(NN / BM, 1, SK2), dim3(256), 0, stream,
                       x2, W2p, Cp2);
    hipLaunchKernelGGL(l2_post, dim3(NN), dim3(64), 0, stream,
                       Cp2, a2sf, a2df, h2, d1, d2);
    hipLaunchKernelGGL(l2_attn, dim3(NN / 4), dim3(256), 0, stream,
                       nbr, deg, h2, d1, d2, (float*)d_out);
}